// Round 1
// 667.248 us; speedup vs baseline: 1.2015x; 1.2015x over previous
//
#include <hip/hip_runtime.h>
#include <stdint.h>

// LSTMNet: B=2048, T=512, IN=64, H=64, 4H=256, 2 layers, FC to 4 classes.
// R5: instruction-diet pass on R4's structure (512 WGs x 512 thr, NB=4,
// waves 0-3 = L0, waves 4-7 = L1 lagging one step, ping-pong panels,
// ONE barrier/iter).
//  - Batch b hi row = 4b, lo row = 4b+1  => lane kg owns batch kg's hi AND lo
//    in acc[g][0]/acc[g][1]; fold = one v_add3 per gate (kills 8 ds_bpermute
//    + 12 VALU per wave-iter).
//  - Persistent z4 C-init kills 16 acc-zero movs/iter.
//  - L1 reads h0 from panel0 cols 64+ directly (64+(kt-2)*32 == kt*32), so
//    L0 no longer mirrors h0 into panel1 (saves 2 ds_write/lane/iter).
//  - Hot-path bf16 split = round-half-up (2 ops); lo absorbs residual.
//  - tanh(x) = 2*rcp(1+exp2(-2.885x)) - 1 (5 ops, no abs/copysign).
//  - x prefetch+staging moved to L1 waves (balances barrier arrival).

#define T_SEQ 512
#define NB    4
#define PSTR  136          // A-panel row stride (bf16): 272B, 16B-aligned b128
#define PANEL (16 * PSTR)

typedef __attribute__((ext_vector_type(8))) short  short8;   // 8 x bf16
typedef __attribute__((ext_vector_type(4))) float  float4v;  // MFMA C/D

__device__ __forceinline__ unsigned short f2bf(float f) {    // RNE (setup only)
    unsigned int u = __builtin_bit_cast(unsigned int, f);
    return (unsigned short)((u + 0x7FFFu + ((u >> 16) & 1u)) >> 16);
}
__device__ __forceinline__ unsigned short f2bf_rhu(float f) { // hot path
    unsigned int u = __builtin_bit_cast(unsigned int, f);
    return (unsigned short)((u + 0x8000u) >> 16);
}
__device__ __forceinline__ float bf2f(unsigned short h) {
    unsigned int u = ((unsigned int)h) << 16;
    return __builtin_bit_cast(float, u);
}
__device__ __forceinline__ float sigm(float x) {
    return __builtin_amdgcn_rcpf(1.0f + __builtin_amdgcn_exp2f(-1.44269504088896f * x));
}
__device__ __forceinline__ float tanh_f(float x) {
    float e = __builtin_amdgcn_exp2f(-2.88539008177793f * x);   // exp(-2x)
    return __builtin_fmaf(2.0f, __builtin_amdgcn_rcpf(1.0f + e), -1.0f);
}

__global__ __launch_bounds__(512, 4) void lstm2_kernel(
    const float* __restrict__ x,
    const float* __restrict__ wih0, const float* __restrict__ whh0,
    const float* __restrict__ bih0, const float* __restrict__ bhh0,
    const float* __restrict__ wih1, const float* __restrict__ whh1,
    const float* __restrict__ bih1, const float* __restrict__ bhh1,
    const float* __restrict__ fcw,  const float* __restrict__ fcb,
    float* __restrict__ out)
{
    // panel0: cols [0,64)=x_t, [64,128)=h_l0.  panel1: cols [64,128)=h_l1
    // (cols [0,64) of panel1 unused; L1 reads h_l0 from panel0 cols 64+).
    // Rows: batch b hi=4b, lo=4b+1; rows 4b+2,4b+3 stay zero.
    __shared__ __align__(16) unsigned short panel0[2][PANEL];
    __shared__ __align__(16) unsigned short panel1[2][PANEL];
    __shared__ float h2buf[NB * 64];
    __shared__ float fcw_s[256];
    __shared__ float fcb_s[4];

    const int tid  = threadIdx.x;
    const int lane = tid & 63;
    const int wave = tid >> 6;
    const int mrow = lane & 15;         // A m-row base / B n-within-tile / C col
    const int kg   = lane >> 4;         // k-quad / C row-group / THIS LANE'S BATCH
    const int lset = wave >> 2;         // 0 = layer-0 waves, 1 = layer-1 waves
    const int ws   = wave & 3;          // h-slice [16*ws, 16*ws+16)
    const int b0   = blockIdx.x * NB;

    for (int i = tid; i < 256; i += 512) fcw_s[i] = fcw[i];
    if (tid < 4) fcb_s[tid] = fcb[tid];
    for (int i = tid; i < 2 * PANEL; i += 512) {
        panel0[0][i] = 0; panel1[0][i] = 0;   // flattened across both buffers
    }

    const float* wih  = lset ? wih1 : wih0;
    const float* whh  = lset ? whh1 : whh0;
    const float* bihp = lset ? bih1 : bih0;
    const float* bhhp = lset ? bhh1 : bhh0;

    // Per-lane gate biases: gate g at n = g*64 + ws*16 + mrow.
    float biasg[4];
    #pragma unroll
    for (int g = 0; g < 4; ++g) {
        const int idx = g * 64 + ws * 16 + mrow;
        biasg[g] = bihp[idx] + bhhp[idx];
    }

    // Weight B-frags (bf16 hi only): wave owns n-tiles {ws,4+ws,8+ws,12+ws}
    // = gates i,f,g,o of its slice. n = tile*16 + mrow, k = kt*32 + kg*8 + j.
    // Combined K=128: k<64 -> w_ih[n][k]; k>=64 -> w_hh[n][k-64].
    short8 whiF[4][4];                  // 64 VGPRs
    #pragma unroll
    for (int g = 0; g < 4; ++g) {
        const int n = (g * 4 + ws) * 16 + mrow;
        #pragma unroll
        for (int kt = 0; kt < 4; ++kt) {
            const int k0 = kt * 32 + kg * 8;
            const float* src = (k0 < 64) ? (wih + n * 64 + k0)
                                         : (whh + n * 64 + (k0 - 64));
            union { short8 s; unsigned short u[8]; } hi8;
            #pragma unroll
            for (int j = 0; j < 8; ++j) hi8.u[j] = f2bf(src[j]);
            whiF[g][kt] = hi8.s;
        }
    }

    __syncthreads();                    // panels zeroed
    if (tid < 256) {                    // stage x(0) into panel0[0]
        const int bx = tid >> 6, kx = tid & 63;
        float xv = x[((size_t)(b0 + bx) * T_SEQ + 0) * 64 + kx];
        unsigned short h = f2bf_rhu(xv);
        panel0[0][(4 * bx) * PSTR + kx]     = h;
        panel0[0][(4 * bx + 1) * PSTR + kx] = f2bf_rhu(xv - bf2f(h));
    }
    __syncthreads();

    // Per-lane constant addressing (shorts).
    const int fragoff = mrow * PSTR + kg * 8;
    const unsigned short* rdA = &panel0[0][0] + (lset ? 64 : 0) + fragoff; // kt 0,1
    const unsigned short* rdB = (lset ? &panel1[0][0] : &panel0[0][0]) + fragoff; // kt 2,3
    unsigned short* hP = lset ? &panel1[0][0] : &panel0[0][0];  // h-write panel
    const int hcol  = ws * 16 + mrow;
    const int hoff0 = (4 * kg) * PSTR + 64 + hcol;   // hi row
    const int hoff1 = hoff0 + PSTR;                  // lo row
    const int bw    = wave & 3;                      // staging batch (L1 waves)
    const int xr0   = (4 * bw) * PSTR + lane;        // x stage hi-row offset
    const float* xp = x + ((size_t)(b0 + bw) * T_SEQ + 1) * 64 + lane;  // t=1
    float c = 0.f;
    const float4v z4 = {0.f, 0.f, 0.f, 0.f};

    for (int s = 0; s <= T_SEQ; ++s) {
        const int p    = s & 1;
        const int poff = p * PANEL;
        const int qoff = poff ^ PANEL;

        // Prefetch x(s+1) (L1 waves; wave-uniform condition).
        const bool do_stage = (lset == 1) && (s + 1 < T_SEQ);
        float xv = 0.f;
        if (do_stage) xv = *xp;

        // ---- MFMA: 4 gate chains, depth 4 ----
        short8 af[4];
        {
            const unsigned short* bA = rdA + poff;
            const unsigned short* bB = rdB + poff;
            af[0] = *(const short8*)(bA);
            af[1] = *(const short8*)(bA + 32);
            af[2] = *(const short8*)(bB + 64);
            af[3] = *(const short8*)(bB + 96);
        }
        float4v acc[4];
        #pragma unroll
        for (int g = 0; g < 4; ++g)
            acc[g] = __builtin_amdgcn_mfma_f32_16x16x32_bf16(af[0], whiF[g][0], z4, 0, 0, 0);
        #pragma unroll
        for (int kt = 1; kt < 4; ++kt) {
            #pragma unroll
            for (int g = 0; g < 4; ++g)
                acc[g] = __builtin_amdgcn_mfma_f32_16x16x32_bf16(af[kt], whiF[g][kt], acc[g], 0, 0, 0);
        }

        // ---- Cell phase (writes go to the OTHER buffer; 1 barrier/iter) ----
        const bool active = lset ? (s > 0) : (s < T_SEQ);
        if (active) {                   // wave-uniform
            // Same-lane hi/lo fold: batch kg hi = C row 4kg (reg 0),
            // lo = C row 4kg+1 (reg 1). No cross-lane ops.
            float g0 = acc[0][0] + acc[0][1] + biasg[0];
            float g1 = acc[1][0] + acc[1][1] + biasg[1];
            float g2 = acc[2][0] + acc[2][1] + biasg[2];
            float g3 = acc[3][0] + acc[3][1] + biasg[3];
            float ig = sigm(g0), fg = sigm(g1);
            float gt = tanh_f(g2), og = sigm(g3);
            c = fg * c + ig * gt;
            float hv = og * tanh_f(c);
            unsigned short hhi = f2bf_rhu(hv);
            unsigned short hlo = f2bf_rhu(hv - bf2f(hhi));
            unsigned short* w = hP + qoff;
            w[hoff0] = hhi;
            w[hoff1] = hlo;
            if (lset && s == T_SEQ) h2buf[(kg << 6) + hcol] = hv;
        }
        if (do_stage) {                 // stage x(s+1) (L1 waves)
            unsigned short xh = f2bf_rhu(xv);
            unsigned short xl = f2bf_rhu(xv - bf2f(xh));
            unsigned short* w0 = &panel0[0][0] + qoff + xr0;
            w0[0]    = xh;
            w0[PSTR] = xl;
            xp += 64;
        }
        __syncthreads();
    }

    // ---- FC head ----
    if (tid < 16) {
        const int bb = tid >> 2, nc = tid & 3;
        float s = fcb_s[nc];
        #pragma unroll 8
        for (int h = 0; h < 64; ++h) s += h2buf[bb * 64 + h] * fcw_s[nc * 64 + h];
        out[(size_t)(b0 + bb) * 4 + nc] = s;
    }
}

extern "C" void kernel_launch(void* const* d_in, const int* in_sizes, int n_in,
                              void* d_out, int out_size, void* d_ws, size_t ws_size,
                              hipStream_t stream) {
    const float* x    = (const float*)d_in[0];
    const float* wih0 = (const float*)d_in[1];
    const float* whh0 = (const float*)d_in[2];
    const float* bih0 = (const float*)d_in[3];
    const float* bhh0 = (const float*)d_in[4];
    const float* wih1 = (const float*)d_in[5];
    const float* whh1 = (const float*)d_in[6];
    const float* bih1 = (const float*)d_in[7];
    const float* bhh1 = (const float*)d_in[8];
    const float* fcw  = (const float*)d_in[9];
    const float* fcb  = (const float*)d_in[10];
    float* out = (float*)d_out;
    (void)d_ws; (void)ws_size; (void)in_sizes; (void)n_in; (void)out_size;

    lstm2_kernel<<<dim3(2048 / NB), dim3(512), 0, stream>>>(
        x, wih0, whh0, bih0, bhh0, wih1, whh1, bih1, bhh1, fcw, fcb, out);
}